// Round 1
// baseline (118.921 us; speedup 1.0000x reference)
//
#include <hip/hip_runtime.h>
#include <stdint.h>

#define BB 4
#define NN 2048
#define F_IN 128
#define F_OUT 256
#define NH 4
#define HD 64

typedef float f32x4 __attribute__((ext_vector_type(4)));
typedef short s16x8 __attribute__((ext_vector_type(8)));
typedef int i32x4 __attribute__((ext_vector_type(4)));
typedef unsigned short u16;

__device__ __forceinline__ u16 f32_to_bf16_rtn(float f) {
    union { float f; uint32_t u; } v; v.f = f;
    uint32_t u = v.u;
    u += 0x7fffu + ((u >> 16) & 1u);
    return (u16)(u >> 16);
}

// K1: h = x @ W^T (fp32), store hT as bf16 [B, F_OUT, N]; fused e_l/e_r via
// wave butterfly (wave w == head w, 64 lanes == that head's HD columns).
__global__ __launch_bounds__(256) void k1_proj(
    const float* __restrict__ x, const float* __restrict__ W,
    const float* __restrict__ a_l, const float* __restrict__ a_r,
    u16* __restrict__ hT, float* __restrict__ el, float* __restrict__ er)
{
    const int t = threadIdx.x;
    const int b = blockIdx.x >> 7;            // 128 n-tiles per batch
    const int n0 = (blockIdx.x & 127) * 16;

    __shared__ __align__(16) float xs[16][F_IN];
    {
        const f32x4* src = (const f32x4*)(x + ((size_t)b * NN + n0) * F_IN);
        f32x4* dst = (f32x4*)&xs[0][0];
        dst[t] = src[t];
        dst[t + 256] = src[t + 256];
    }
    __syncthreads();

    float acc[16];
#pragma unroll
    for (int n = 0; n < 16; ++n) acc[n] = 0.f;

    const float* wrow = W + (size_t)t * F_IN;
#pragma unroll 4
    for (int k0 = 0; k0 < F_IN; k0 += 8) {
        f32x4 w0 = *(const f32x4*)(wrow + k0);
        f32x4 w1 = *(const f32x4*)(wrow + k0 + 4);
#pragma unroll
        for (int n = 0; n < 16; ++n) {
            f32x4 xa = *(const f32x4*)&xs[n][k0];
            f32x4 xb = *(const f32x4*)&xs[n][k0 + 4];
            float s = acc[n];
            s += xa[0]*w0[0]; s += xa[1]*w0[1]; s += xa[2]*w0[2]; s += xa[3]*w0[3];
            s += xb[0]*w1[0]; s += xb[1]*w1[1]; s += xb[2]*w1[2]; s += xb[3]*w1[3];
            acc[n] = s;
        }
    }

    // e_l / e_r: wave w covers head w's 64 dims; butterfly-sum over lanes.
    const int w = t >> 6, lane = t & 63;
    const float al = a_l[t];   // flat [H][HD], o == t
    const float ar = a_r[t];
    float my_el = 0.f, my_er = 0.f;
#pragma unroll
    for (int n = 0; n < 16; ++n) {
        float vl = acc[n] * al;
        float vr = acc[n] * ar;
#pragma unroll
        for (int off = 32; off; off >>= 1) {
            vl += __shfl_xor(vl, off, 64);
            vr += __shfl_xor(vr, off, 64);
        }
        if (lane == n) { my_el = vl; my_er = vr; }
    }
    if (lane < 16) {
        el[((size_t)b * NH + w) * NN + n0 + lane] = my_el;
        er[((size_t)b * NH + w) * NN + n0 + lane] = my_er;
    }

    // hT bf16 [B, F_OUT, N]: thread t owns row o=t, 16 consecutive n.
    u16* hrow = hT + ((size_t)b * F_OUT + t) * NN + n0;
    s16x8 pk0, pk1;
#pragma unroll
    for (int n = 0; n < 8; ++n) pk0[n] = (short)f32_to_bf16_rtn(acc[n]);
#pragma unroll
    for (int n = 0; n < 8; ++n) pk1[n] = (short)f32_to_bf16_rtn(acc[n + 8]);
    *(s16x8*)hrow = pk0;
    *(s16x8*)(hrow + 8) = pk1;
}

// K2: fused masked softmax + aggregation. Block = (b, 16-row i-tile);
// wave = head. Per 32-j step: generate P fragment in registers, 4 MFMAs.
__global__ __launch_bounds__(256) void k2_attn(
    const int* __restrict__ adj, const u16* __restrict__ hT,
    const float* __restrict__ el, const float* __restrict__ er,
    float* __restrict__ out)
{
    const int t = threadIdx.x;
    const int w = t >> 6;          // head
    const int l = t & 63;
    const int b = blockIdx.x >> 7;
    const int i0 = (blockIdx.x & 127) * 16;
    const int r  = l & 15;         // A-frag row / D col
    const int ks = (l >> 4) * 8;   // k-slice start within 32-j step

    const float el_i = el[((size_t)b * NH + w) * NN + i0 + r];
    const float* erp = er + ((size_t)b * NH + w) * NN + ks;
    const int*  adjp = adj + ((size_t)b * NN + i0 + r) * NN + ks;
    const u16*  hp   = hT + ((size_t)b * F_OUT + w * HD + r) * NN + ks;

    f32x4 acc0 = {0.f,0.f,0.f,0.f}, acc1 = acc0, acc2 = acc0, acc3 = acc0;
    float rowsum = 0.f;

    for (int jt = 0; jt < NN / 32; ++jt) {
        i32x4 a0 = *(const i32x4*)adjp;
        i32x4 a1 = *(const i32x4*)(adjp + 4);
        f32x4 e0 = *(const f32x4*)erp;
        f32x4 e1 = *(const f32x4*)(erp + 4);
        s16x8 b0 = *(const s16x8*)(hp);
        s16x8 b1 = *(const s16x8*)(hp + 16 * NN);
        s16x8 b2 = *(const s16x8*)(hp + 32 * NN);
        s16x8 b3 = *(const s16x8*)(hp + 48 * NN);

        s16x8 afrag;
#pragma unroll
        for (int k = 0; k < 8; ++k) {
            float e_j = (k < 4) ? e0[k] : e1[k - 4];
            int   av  = (k < 4) ? a0[k] : a1[k - 4];
            float s = el_i + e_j;
            s = fmaxf(s, 0.2f * s);          // leaky_relu(0.2)
            float pe = __expf(s);
            pe = av ? pe : 0.f;              // adjacency mask
            rowsum += pe;
            afrag[k] = (short)f32_to_bf16_rtn(pe);
        }

        acc0 = __builtin_amdgcn_mfma_f32_16x16x32_bf16(afrag, b0, acc0, 0, 0, 0);
        acc1 = __builtin_amdgcn_mfma_f32_16x16x32_bf16(afrag, b1, acc1, 0, 0, 0);
        acc2 = __builtin_amdgcn_mfma_f32_16x16x32_bf16(afrag, b2, acc2, 0, 0, 0);
        acc3 = __builtin_amdgcn_mfma_f32_16x16x32_bf16(afrag, b3, acc3, 0, 0, 0);

        adjp += 32; erp += 32; hp += 32;
    }

    // full row sums: combine the 4 k-slice lanes sharing (l&15)
    rowsum += __shfl_xor(rowsum, 16, 64);
    rowsum += __shfl_xor(rowsum, 32, 64);

    float* op = out + ((size_t)b * NN + i0) * F_OUT + w * HD;
#pragma unroll
    for (int q = 0; q < 4; ++q) {
        const int row = (l >> 4) * 4 + q;    // D row for acc[q]
        float rs = __shfl(rowsum, row, 64);  // lane `row` holds row `row`'s sum
        float inv = 1.0f / rs;
        op[(size_t)row * F_OUT +  0 + r] = acc0[q] * inv;
        op[(size_t)row * F_OUT + 16 + r] = acc1[q] * inv;
        op[(size_t)row * F_OUT + 32 + r] = acc2[q] * inv;
        op[(size_t)row * F_OUT + 48 + r] = acc3[q] * inv;
    }
}

extern "C" void kernel_launch(void* const* d_in, const int* in_sizes, int n_in,
                              void* d_out, int out_size, void* d_ws, size_t ws_size,
                              hipStream_t stream) {
    const float* x   = (const float*)d_in[0];
    const int*   adj = (const int*)d_in[1];
    const float* W   = (const float*)d_in[2];
    const float* a_l = (const float*)d_in[3];
    const float* a_r = (const float*)d_in[4];
    float* out = (float*)d_out;

    u16*   hT = (u16*)d_ws;
    float* el = (float*)((char*)d_ws + (size_t)BB * F_OUT * NN * sizeof(u16));
    float* er = el + (size_t)BB * NH * NN;

    k1_proj<<<BB * (NN / 16), 256, 0, stream>>>(x, W, a_l, a_r, hT, el, er);
    k2_attn<<<BB * (NN / 16), 256, 0, stream>>>(adj, hT, el, er, out);
}